// Round 15
// baseline (147.564 us; speedup 1.0000x reference)
//
#include <hip/hip_runtime.h>
#include <cmath>
#include <climits>

// Fixed problem shape
#define L_    8
#define B_    4
#define T_    2048
#define D_    1024
#define TTL_  1024
#define KSLOT 512
#define EVCAP 512
#define TCQ   8            // rows per mark-descriptor chunk
#define NCQ   (T_/TCQ)     // 256
#define GRPC  4            // chunks per kSQ group (32 rows)
#define NGRP  64           // groups per (l,b)
#define MKCAP 192          // marks per 32-row group (proven <=127)
#define TIEMAX 256
#define MAXMB 1024

__device__ __forceinline__ int waveRed(int v){
  for(int o=32;o>0;o>>=1) v += __shfl_xor(v,o,64);
  return v;
}
__device__ __forceinline__ int lowb_s(const short* a, int n, int v){
  int lo=0, hi=n;
  while(lo<hi){ int mid=(lo+hi)>>1; if((int)a[mid] < v) lo=mid+1; else hi=mid; }
  return lo;
}
__device__ __forceinline__ int uppb_s(const short* a, int n, int v){
  int lo=0, hi=n;
  while(lo<hi){ int mid=(lo+hi)>>1; if((int)a[mid] <= v) lo=mid+1; else hi=mid; }
  return lo;
}

// ---------------------------------------------------------------------------
// Kernel A (unchanged except evCS/evCE now store 32-row GROUP indices).
// ---------------------------------------------------------------------------
__global__ __launch_bounds__(1024) void kA(
    const float* __restrict__ pressure, const int* __restrict__ hptr, int k,
    int* __restrict__ meta, float* __restrict__ w,
    int* __restrict__ evB, int* __restrict__ evCS, int* __restrict__ evCE,
    float* __restrict__ evInv,
    unsigned short* __restrict__ markRowG, unsigned short* __restrict__ markValG,
    int* __restrict__ mkStart, int* __restrict__ mkCnt)
{
  __shared__ unsigned ku[B_*T_];
  __shared__ short ef[B_*T_];
  __shared__ int csum[1024];
  __shared__ int cnt4[4][4];
  __shared__ int scnt;
  __shared__ int s_n[B_], s_off[B_];
  __shared__ int batchPfx[B_+1];
  __shared__ int tieIdx[TIEMAX];
  __shared__ int tieCnt;
  __shared__ short evTeSh[B_*KSLOT];
  __shared__ short evEnSh[B_*KSLOT];
  const int tid = threadIdx.x;
  const int total = B_*T_;
  const int H = hptr[0];

  for(int i=tid;i<total;i+=1024){
    union{float f;unsigned u;} v; v.f = pressure[i];
    unsigned u = v.u;
    ku[i] = (u & 0x80000000u) ? ~u : (u | 0x80000000u);
  }
  if(tid < B_) s_n[tid] = 0;
  if(tid == 0) tieCnt = 0;
  if(tid < 8) ((int*)cnt4)[tid] = 0;
  __syncthreads();

  unsigned p = 0;
  for(int it=0; it<16; ++it){
    const int bit = 30 - 2*it;
    int* A = cnt4[it&3];
    const unsigned q1 = p | (1u<<bit);
    const unsigned q2 = p | (2u<<bit);
    const unsigned q3 = p | (3u<<bit);
    int c1=0,c2=0,c3=0;
    for(int i=tid;i<total;i+=1024){
      unsigned x = ku[i];
      c1 += (x>=q1); c2 += (x>=q2); c3 += (x>=q3);
    }
    c1=waveRed(c1); c2=waveRed(c2); c3=waveRed(c3);
    if((tid&63)==0){ atomicAdd(&A[1],c1); atomicAdd(&A[2],c2); atomicAdd(&A[3],c3); }
    if(tid<4) cnt4[(it+2)&3][tid] = 0;
    __syncthreads();
    const int n1=A[1], n2=A[2], n3=A[3];
    if(n3>=k) p=q3; else if(n2>=k) p=q2; else if(n1>=k) p=q1;
  }
  __syncthreads();
  if(tid==0) scnt=0;
  __syncthreads();
  {
    int c=0;
    for(int i=tid;i<total;i+=1024) c += (ku[i] > p) ? 1 : 0;
    c = waveRed(c);
    if((tid&63)==0) atomicAdd(&scnt, c);
  }
  for(int i=tid;i<total;i+=1024){
    if(ku[i]==p){ int pos=atomicAdd(&tieCnt,1); if(pos<TIEMAX) tieIdx[pos]=i; }
  }
  __syncthreads();
  const int needed = k - scnt;

  for(int j=0;j<8;++j){
    int i = tid*8+j;
    ef[i] = (ku[i] > p) ? (short)1 : (short)0;
  }
  __syncthreads();

  if(tieCnt <= TIEMAX){
    if(tid==0){
      int cnt = tieCnt;
      for(int sel=0; sel<needed; ++sel){
        int best=INT_MAX, bi=-1;
        for(int q=0;q<cnt;++q){ int vv=tieIdx[q]; if(vv>=0 && vv<best){best=vv;bi=q;} }
        if(bi>=0){ tieIdx[bi]=-1; ef[best]=1; }
      }
    }
  } else {
    for(int j=0;j<8;++j){
      int i = tid*8+j;
      if(ku[i]==p){
        int r=0;
        for(int q=0;q<i;++q) r += (ku[q]==p) ? 1 : 0;
        if(r < needed) ef[i]=1;
      }
    }
  }
  __syncthreads();

  int own = 0;
  #pragma unroll
  for(int j=0;j<8;++j) own += ef[tid*8+j];
  csum[tid] = own;
  __syncthreads();
  for(int ofs=1; ofs<1024; ofs<<=1){
    int add = (tid>=ofs) ? csum[tid-ofs] : 0;
    __syncthreads();
    csum[tid] += add;
    __syncthreads();
  }
  if(tid < B_) batchPfx[tid] = (tid==0) ? 0 : csum[tid*256-1];
  if(tid == 0) batchPfx[B_] = csum[1023];
  __syncthreads();

  {
    const int ex = csum[tid] - own;
    int run = 0;
    for(int j=0;j<8;++j){
      int i = tid*8+j;
      if(ef[i]){
        int b = i >> 11;
        int t = i & (T_-1);
        int m = ex + run - batchPfx[b];
        if(t != T_-1){
          int c = T_-1-t; if(c>H) c=H;
          evTeSh[b*KSLOT+m] = (short)t;
          evEnSh[b*KSLOT+m] = (short)(t+c);
        }
        ++run;
      }
    }
  }
  __syncthreads();
  if(tid < B_){
    int nf = batchPfx[tid+1] - batchPfx[tid];
    nf -= (ef[tid*T_ + T_-1] ? 1 : 0);
    s_n[tid] = nf;
  }
  __syncthreads();
  if(tid==0){
    int off=0;
    for(int b=0;b<B_;++b){ meta[b]=s_n[b]; meta[4+b]=off; s_off[b]=off; off += s_n[b]; }
    meta[8] = off;  // nev
  }
  __syncthreads();

  for(int idx=tid; idx<B_*MAXMB; idx+=1024){
    const int b = idx>>10, m = idx & (MAXMB-1);
    const int n = s_n[b];
    if(m >= 2*n) continue;
    const short* S = evTeSh + b*KSLOT;
    const short* E = evEnSh + b*KSLOT;
    int rank, row, val;
    if(m < n){
      row = (int)S[m];
      rank = m + lowb_s(E, n, row);
      const int e = s_off[b] + m;
      val = e;
      const int en = (int)E[m];
      evB[e]=b; evCS[e]=row>>5; evCE[e]=en>>5;   // 32-row GROUP indices
      evInv[e] = 1.0f/(float)(en - row);
    } else {
      const int j = m - n;
      row = (int)E[j];
      rank = uppb_s(S, n, row) + j;
      val = (s_off[b] + j) | 0x8000;
    }
    markRowG[b*MAXMB+rank] = (unsigned short)row;
    markValG[b*MAXMB+rank] = (unsigned short)val;
  }

  for(int idx=tid; idx<B_*NCQ; idx+=1024){
    const int b = idx/NCQ, ch = idx%NCQ;
    const int n = s_n[b];
    const short* S = evTeSh + b*KSLOT;
    const short* E = evEnSh + b*KSLOT;
    const int lo = ch*TCQ, hi = lo+TCQ;
    const int a = lowb_s(S,n,lo) + lowb_s(E,n,lo);
    const int c = lowb_s(S,n,hi) + lowb_s(E,n,hi);
    mkStart[idx] = a; mkCnt[idx] = c - a;
  }

  for(int s=tid;s<T_;s+=1024){
    float acc = 0.f;
    int lo = s - H; if(lo < 0) lo = 0;
    for(int t2=lo; t2<s; ++t2){
      int c2 = T_-1-t2; if(c2 > H) c2 = H;
      acc += 1.0f / (float)c2;
    }
    w[s] = acc;
  }
}

// ---------------------------------------------------------------------------
// Kernel SQ v4: same barrier-free per-wave pipeline as R14 but HALVED
// footprint for 2x resident DMA waves: 32-row groups, 2-row batches,
// 2 slots x 2 rows = 16KB LDS (+<1KB marks) -> ~8-9 blocks/CU (~32 waves
// issuing DMA vs 16). Counted vmcnt(2). Grid 2048.
// ---------------------------------------------------------------------------
__global__ __launch_bounds__(256) void kSQ(
    const float* __restrict__ states, const float* __restrict__ w,
    const int* __restrict__ mkStart, const int* __restrict__ mkCnt,
    const unsigned short* __restrict__ markRowG,
    const unsigned short* __restrict__ markValG,
    float4* __restrict__ Gbuf, float4* __restrict__ wA,
    float4* __restrict__ feS, float4* __restrict__ feE)
{
  __shared__ float lds[2][2][1024];        // 16 KB
  __shared__ unsigned short sMr[MKCAP];
  __shared__ unsigned short sMv[MKCAP];
  __shared__ float sW[32];

  int bx = blockIdx.x;
  const int grp = bx & (NGRP-1); bx >>= 6;
  const int b = bx & 3; const int l = bx >> 2;
  const int tid = threadIdx.x;
  const int wv = tid >> 6, lane = tid & 63;
  const int t0 = grp * 32;
  const float* sbase = states + ((size_t)(l*B_+b)*T_ + t0)*D_;

  const int gBase = (b<<8) + grp*GRPC;
  const int mi0 = mkStart[gBase];
  int cnt = (mkStart[gBase+GRPC-1] + mkCnt[gBase+GRPC-1]) - mi0;
  if(cnt > MKCAP) cnt = MKCAP;   // mathematically <=127; hard guard
  for(int i=tid; i<cnt; i+=256){
    sMr[i] = markRowG[b*MAXMB + mi0 + i];
    sMv[i] = markValG[b*MAXMB + mi0 + i];
  }
  if(tid < 32) sW[tid] = w[t0 + tid];
  __syncthreads();   // drains vmcnt+lgkmcnt: counters clean before pipeline

  int mi = 0;
  int nextRow = (cnt > 0) ? (int)sMr[0] : INT_MAX;
  float4 R={0,0,0,0}, A={0,0,0,0};

#define ISSUE(slot_, batch_) { _Pragma("unroll") \
  for(int r_=0;r_<2;++r_){ \
    const float* g_ = sbase + (size_t)((batch_)*2 + r_)*D_ + wv*256 + lane*4; \
    __builtin_amdgcn_global_load_lds( \
        (const __attribute__((address_space(1))) void*)g_, \
        (__attribute__((address_space(3))) void*)&lds[slot_][r_][wv*256], \
        16, 0, 0); } }

#define ROW(j_, xv_) { \
    const int t = t0 + bb*2 + (j_); \
    float sx=xv_.x*xv_.x, sy=xv_.y*xv_.y, sz=xv_.z*xv_.z, sw=xv_.w*xv_.w; \
    R.x+=sx; R.y+=sy; R.z+=sz; R.w+=sw; \
    const float wj = sW[bb*2 + (j_)]; \
    A.x=fmaf(wj,sx,A.x); A.y=fmaf(wj,sy,A.y); \
    A.z=fmaf(wj,sz,A.z); A.w=fmaf(wj,sw,A.w); \
    while(nextRow == t){ \
      const int me = (int)sMv[mi]; \
      float4* dst = (me & 0x8000) ? feE : feS; \
      dst[((size_t)l*EVCAP + (me & 0x7fff))*256 + tid] = R; \
      ++mi; nextRow = (mi < cnt) ? (int)sMr[mi] : INT_MAX; } }

  ISSUE(0,0); ISSUE(1,1);   // 4 loads outstanding per wave

  #pragma unroll
  for(int bb=0; bb<16; ++bb){
    if(bb < 15){ asm volatile("s_waitcnt vmcnt(2)" ::: "memory"); }
    else       { asm volatile("s_waitcnt vmcnt(0)" ::: "memory"); }
    __builtin_amdgcn_sched_barrier(0);
    const int slot = bb & 1;
    float4 x0 = *(const float4*)&lds[slot][0][tid*4];
    float4 x1 = *(const float4*)&lds[slot][1][tid*4];
    asm volatile("s_waitcnt lgkmcnt(0)" ::: "memory");
    __builtin_amdgcn_sched_barrier(0);
    if(bb+2 < 16){ ISSUE(slot, bb+2); }   // prefetch BEFORE stores
    ROW(0,x0) ROW(1,x1)
  }
  const size_t gi = ((size_t)(l*B_+b)*NGRP + grp)*256 + tid;
  Gbuf[gi] = R;    // 32-row group total
  wA[gi]   = A;
#undef ISSUE
#undef ROW
}

// ---------------------------------------------------------------------------
// Kernel Fin (fused): blocks [0,128): reduce wA (64 group-rows) -> S_allP.
// blocks [128,384): per-(l,es) finalize fe AND produce S_evP partial row.
// Window <=64 rows spans <=3 groups: fe = (G[gs]-Rs) + sum(G interior) + Re,
// all window-local magnitudes. No atomics.
// ---------------------------------------------------------------------------
__global__ __launch_bounds__(256) void kFin(
    const float* __restrict__ wAf, float* __restrict__ S_allP,
    const float4* __restrict__ Gbuf,
    const float4* __restrict__ feS, float4* __restrict__ feE,
    const int* __restrict__ evB, const int* __restrict__ evCS,
    const int* __restrict__ evCE, const float* __restrict__ evInv,
    const int* __restrict__ meta, float4* __restrict__ S_evP)
{
  const int tid = threadIdx.x;
  if(blockIdx.x < 128){
    const int dq = blockIdx.x & 3; const int lb = blockIdx.x >> 2;
    const int d = dq*256 + tid;
    const size_t base = (size_t)lb*NGRP*D_ + d;
    float aw = 0.f;
    for(int g0=0; g0<NGRP; g0+=8){
      float t[8];
      #pragma unroll
      for(int j=0;j<8;++j) t[j] = wAf[base + (size_t)(g0+j)*D_];
      #pragma unroll
      for(int j=0;j<8;++j) aw += t[j];
    }
    S_allP[(size_t)lb*D_ + d] = aw;
  } else {
    const int bid = blockIdx.x - 128;
    const int es = bid & 31; const int l = bid >> 5;
    const int nev = meta[8];
    const int per = (nev + 31) >> 5;
    const int e0 = es*per;
    int e1 = e0 + per; if(e1 > nev) e1 = nev;
    float4 E = {0,0,0,0};
    for(int e=e0; e<e1; ++e){
      const int b = evB[e], gs = evCS[e], ge = evCE[e];
      const float inv = evInv[e];
      const size_t sl = ((size_t)l*EVCAP + e)*256 + tid;
      float4 Rs = feS[sl], Re = feE[sl];
      float4 fe;
      if(gs == ge){
        fe.x=(Re.x-Rs.x)*inv; fe.y=(Re.y-Rs.y)*inv;
        fe.z=(Re.z-Rs.z)*inv; fe.w=(Re.w-Rs.w)*inv;
      } else {
        const size_t gb = ((size_t)(l*B_+b)*NGRP)*256 + tid;
        float4 acc = Gbuf[gb + (size_t)gs*256];
        acc.x-=Rs.x; acc.y-=Rs.y; acc.z-=Rs.z; acc.w-=Rs.w;
        for(int g=gs+1; g<ge; ++g){   // <=1 iteration (window <=64 rows)
          float4 Gv = Gbuf[gb + (size_t)g*256];
          acc.x+=Gv.x; acc.y+=Gv.y; acc.z+=Gv.z; acc.w+=Gv.w;
        }
        fe.x=(acc.x+Re.x)*inv; fe.y=(acc.y+Re.y)*inv;
        fe.z=(acc.z+Re.z)*inv; fe.w=(acc.w+Re.w)*inv;
      }
      feE[sl] = fe;
      E.x+=fe.x; E.y+=fe.y; E.z+=fe.z; E.w+=fe.w;
    }
    S_evP[((size_t)l*32 + es)*256 + tid] = E;
  }
}

// ---------------------------------------------------------------------------
// Kernel DS2: blocks [0,256): nb + excess partials; [256,512): bank partials.
// ---------------------------------------------------------------------------
__global__ __launch_bounds__(256) void kDS2(
    const float4* __restrict__ feE, const int* __restrict__ meta,
    const float4* __restrict__ S_allP, const float4* __restrict__ S_evP,
    const float4* __restrict__ baseline4,
    const float4* __restrict__ bank_ev4, const int* __restrict__ bank_step,
    const int* __restrict__ csptr,
    float4* __restrict__ out4, float4* __restrict__ S_exP,
    float4* __restrict__ SscoreP, int nonk)
{
  const int tid = threadIdx.x;
  if(blockIdx.x < 256){
    const int l = blockIdx.x >> 5, ech = blockIdx.x & 31;
    float4 sa = {0,0,0,0};
    #pragma unroll
    for(int b=0;b<B_;++b){
      float4 t = S_allP[((size_t)(l*B_+b))*256 + tid];
      sa.x+=t.x; sa.y+=t.y; sa.z+=t.z; sa.w+=t.w;
    }
    float4 se = {0,0,0,0};
    for(int j0=0;j0<32;j0+=8){
      float4 t[8];
      #pragma unroll
      for(int j=0;j<8;++j) t[j] = S_evP[((size_t)l*32 + j0+j)*256 + tid];
      #pragma unroll
      for(int j=0;j<8;++j){ se.x+=t[j].x; se.y+=t[j].y; se.z+=t[j].z; se.w+=t[j].w; }
    }
    const float inv_nonk = 1.0f/(float)nonk;
    const float4 bl = baseline4[(size_t)l*256 + tid];
    float4 nb;
    nb.x = 0.99f*bl.x + 0.01f*((sa.x-se.x)*inv_nonk);
    nb.y = 0.99f*bl.y + 0.01f*((sa.y-se.y)*inv_nonk);
    nb.z = 0.99f*bl.z + 0.01f*((sa.z-se.z)*inv_nonk);
    nb.w = 0.99f*bl.w + 0.01f*((sa.w-se.w)*inv_nonk);
    if(ech == 0) out4[2048 + (size_t)l*256 + tid] = nb;
    const int nev = meta[8];
    const int per = (nev + 31) >> 5;
    const int e0 = ech*per;
    int e1 = e0 + per; if(e1 > nev) e1 = nev;
    float4 acc = {0,0,0,0};
    #pragma unroll 4
    for(int e=e0;e<e1;++e){
      float4 fe = feE[((size_t)l*EVCAP + e)*256 + tid];
      acc.x += fmaxf(fe.x - nb.x, 0.f);
      acc.y += fmaxf(fe.y - nb.y, 0.f);
      acc.z += fmaxf(fe.z - nb.z, 0.f);
      acc.w += fmaxf(fe.w - nb.w, 0.f);
    }
    S_exP[((size_t)l*32 + ech)*256 + tid] = acc;
  } else {
    const int bx = blockIdx.x - 256;
    const int l = bx >> 5, sch = bx & 31;
    const int scount = TTL_/32;   // 32
    const int s0 = sch*scount;
    __shared__ float wl[TTL_/32];
    const int cs = csptr[0];
    if(tid < scount){
      int bs = bank_step[l*TTL_ + s0 + tid];
      float wgt = 0.f;
      if(bs >= 0){
        int a = cs - bs; if(a < 0) a = 0;
        wgt = exp2f(-(float)a * (1.0f/256.0f));
      }
      wl[tid] = wgt;
    }
    __syncthreads();
    float4 acc = {0,0,0,0};
    const float4* bp = bank_ev4 + ((size_t)l*TTL_ + s0)*256 + tid;
    #pragma unroll 8
    for(int j=0;j<scount;++j){
      float4 v = bp[(size_t)j*256];
      const float wv = wl[j];
      acc.x = fmaf(wv, v.x, acc.x); acc.y = fmaf(wv, v.y, acc.y);
      acc.z = fmaf(wv, v.z, acc.z); acc.w = fmaf(wv, v.w, acc.w);
    }
    SscoreP[((size_t)l*32 + sch)*256 + tid] = acc;
  }
}

// ---------------------------------------------------------------------------
// Kernel E: sum partials; evidence -> out[0], score -> out[2]. grid = L_.
// ---------------------------------------------------------------------------
__global__ __launch_bounds__(256) void kE(
    const float4* __restrict__ S_exP, const float4* __restrict__ SscoreP,
    const int* __restrict__ bank_step, const int* __restrict__ csptr,
    float4* __restrict__ out4, float kf)
{
  const int l = blockIdx.x;
  const int tid = threadIdx.x;
  __shared__ float red[256];
  const int cs = csptr[0];
  float wacc = 0.f;
  for(int s=tid; s<TTL_; s+=256){
    int bs = bank_step[l*TTL_+s];
    if(bs >= 0){
      int a = cs - bs; if(a<0) a=0;
      wacc += exp2f(-(float)a * (1.0f/256.0f));
    }
  }
  red[tid] = wacc;
  __syncthreads();
  for(int st=128; st>0; st>>=1){ if(tid<st) red[tid] += red[tid+st]; __syncthreads(); }
  const float wsum = red[0];

  float4 ex = {0,0,0,0}, ss = {0,0,0,0};
  for(int j0=0;j0<32;j0+=8){
    float4 a[8], bb[8];
    #pragma unroll
    for(int j=0;j<8;++j){
      a[j]  = S_exP[((size_t)l*32 + j0+j)*256 + tid];
      bb[j] = SscoreP[((size_t)l*32 + j0+j)*256 + tid];
    }
    #pragma unroll
    for(int j=0;j<8;++j){
      ex.x+=a[j].x; ex.y+=a[j].y; ex.z+=a[j].z; ex.w+=a[j].w;
      ss.x+=bb[j].x; ss.y+=bb[j].y; ss.z+=bb[j].z; ss.w+=bb[j].w;
    }
  }
  const float invk = 1.0f/kf;
  float4 o0 = {ex.x*invk, ex.y*invk, ex.z*invk, ex.w*invk};
  out4[(size_t)l*256 + tid] = o0;
  float4 o2 = {0,0,0,0};
  if(wsum > 0.f){
    const float wm = fmaxf(wsum, 1e-12f);
    o2.x = ss.x/wm; o2.y = ss.y/wm; o2.z = ss.z/wm; o2.w = ss.w/wm;
  }
  out4[2*2048 + (size_t)l*256 + tid] = o2;
}

// ---------------------------------------------------------------------------
extern "C" void kernel_launch(void* const* d_in, const int* in_sizes, int n_in,
                              void* d_out, int out_size, void* d_ws, size_t ws_size,
                              hipStream_t stream)
{
  const float* pressure  = (const float*)d_in[0];
  const float* states    = (const float*)d_in[1];
  const float* bank_ev   = (const float*)d_in[2];
  const float* baseline  = (const float*)d_in[3];
  const int*   bank_step = (const int*)d_in[4];
  const int*   csptr     = (const int*)d_in[5];
  const int*   hptr      = (const int*)d_in[6];
  float* out = (float*)d_out;

  const int total = B_*T_;
  const int k = (int)llround(0.05 * (double)total);   // 410

  // workspace layout (bytes) — overlap-audited with explicit ends:
  //   w        0        + 8192     -> 8192
  //   meta     8192     + 64       -> 8256
  //   evB      16384    + 2048     -> 18432
  //   evCS     18432    + 2048     -> 20480
  //   evCE     20480    + 2048     -> 22528
  //   evInv    22528    + 2048     -> 24576
  //   markRowG 24576    + 8192     -> 32768
  //   markValG 32768    + 8192     -> 40960
  //   mkStart  40960    + 4096     -> 45056
  //   mkCnt    45056    + 4096     -> 49152
  //   S_allP   65536    + 131072   -> 196608
  //   S_evP    262144   + 1048576  -> 1310720
  //   S_exP    1310720  + 1048576  -> 2359296
  //   SscoreP  2359296  + 1048576  -> 3407872
  //   Gbuf     4194304  + 8388608  -> 12582912   (32 lb x 64 grp x 4KB)
  //   wAbuf    12582912 + 8388608  -> 20971520
  //   feS      20971520 + 16777216 -> 37748736
  //   feE      37748736 + 16777216 -> 54525952
  char* ws = (char*)d_ws;
  float* w        = (float*)(ws + 0);
  int*   meta     = (int*)(ws + 8192);
  int*   evB      = (int*)(ws + 16384);
  int*   evCS     = (int*)(ws + 18432);
  int*   evCE     = (int*)(ws + 20480);
  float* evInv    = (float*)(ws + 22528);
  unsigned short* markRowG = (unsigned short*)(ws + 24576);
  unsigned short* markValG = (unsigned short*)(ws + 32768);
  int*   mkStart  = (int*)(ws + 40960);
  int*   mkCnt    = (int*)(ws + 45056);
  float* S_allP   = (float*)(ws + 65536);
  float* S_evP    = (float*)(ws + 262144);
  float* S_exP    = (float*)(ws + 1310720);
  float* SscoreP  = (float*)(ws + 2359296);
  float* Gbuf     = (float*)(ws + 4194304);
  float* wAbuf    = (float*)(ws + 12582912);
  float* feS      = (float*)(ws + 20971520);
  float* feE      = (float*)(ws + 37748736);

  const size_t need = 54525952ull;  // 52 MB
  if(ws_size < need) return;

  kA<<<1, 1024, 0, stream>>>(pressure, hptr, k, meta, w,
                             evB, evCS, evCE, evInv,
                             markRowG, markValG, mkStart, mkCnt);
  kSQ<<<L_*B_*NGRP, 256, 0, stream>>>(states, w, mkStart, mkCnt,
                                      markRowG, markValG,
                                      (float4*)Gbuf, (float4*)wAbuf,
                                      (float4*)feS, (float4*)feE);
  kFin<<<128 + 256, 256, 0, stream>>>(wAbuf, S_allP,
                                      (const float4*)Gbuf,
                                      (const float4*)feS, (float4*)feE,
                                      evB, evCS, evCE, evInv, meta,
                                      (float4*)S_evP);
  kDS2<<<512, 256, 0, stream>>>((const float4*)feE, meta,
                                (const float4*)S_allP, (const float4*)S_evP,
                                (const float4*)baseline,
                                (const float4*)bank_ev, bank_step, csptr,
                                (float4*)out, (float4*)S_exP,
                                (float4*)SscoreP, total - k);
  kE<<<L_, 256, 0, stream>>>((const float4*)S_exP, (const float4*)SscoreP,
                             bank_step, csptr, (float4*)out, (float)k);
}

// Round 16
// 141.071 us; speedup vs baseline: 1.0460x; 1.0460x over previous
//
#include <hip/hip_runtime.h>
#include <cmath>
#include <climits>

// Fixed problem shape
#define L_    8
#define B_    4
#define T_    2048
#define D_    1024
#define TTL_  1024
#define KSLOT 512
#define EVCAP 512
#define TCQ   8            // rows per mark-descriptor chunk
#define NCQ   (T_/TCQ)     // 256
#define GRPC  4            // chunks per kSQ group (32 rows)
#define NGRP  64           // groups per (l,b)
#define MKCAP 192          // marks per 32-row group (proven <=127)
#define TIEMAX 256
#define MAXMB 1024

typedef float f32x4 __attribute__((ext_vector_type(4)));

__device__ __forceinline__ int waveRed(int v){
  for(int o=32;o>0;o>>=1) v += __shfl_xor(v,o,64);
  return v;
}
__device__ __forceinline__ int lowb_s(const short* a, int n, int v){
  int lo=0, hi=n;
  while(lo<hi){ int mid=(lo+hi)>>1; if((int)a[mid] < v) lo=mid+1; else hi=mid; }
  return lo;
}
__device__ __forceinline__ int uppb_s(const short* a, int n, int v){
  int lo=0, hi=n;
  while(lo<hi){ int mid=(lo+hi)>>1; if((int)a[mid] <= v) lo=mid+1; else hi=mid; }
  return lo;
}

// ---------------------------------------------------------------------------
// Kernel A (byte-identical to R15).
// ---------------------------------------------------------------------------
__global__ __launch_bounds__(1024) void kA(
    const float* __restrict__ pressure, const int* __restrict__ hptr, int k,
    int* __restrict__ meta, float* __restrict__ w,
    int* __restrict__ evB, int* __restrict__ evCS, int* __restrict__ evCE,
    float* __restrict__ evInv,
    unsigned short* __restrict__ markRowG, unsigned short* __restrict__ markValG,
    int* __restrict__ mkStart, int* __restrict__ mkCnt)
{
  __shared__ unsigned ku[B_*T_];
  __shared__ short ef[B_*T_];
  __shared__ int csum[1024];
  __shared__ int cnt4[4][4];
  __shared__ int scnt;
  __shared__ int s_n[B_], s_off[B_];
  __shared__ int batchPfx[B_+1];
  __shared__ int tieIdx[TIEMAX];
  __shared__ int tieCnt;
  __shared__ short evTeSh[B_*KSLOT];
  __shared__ short evEnSh[B_*KSLOT];
  const int tid = threadIdx.x;
  const int total = B_*T_;
  const int H = hptr[0];

  for(int i=tid;i<total;i+=1024){
    union{float f;unsigned u;} v; v.f = pressure[i];
    unsigned u = v.u;
    ku[i] = (u & 0x80000000u) ? ~u : (u | 0x80000000u);
  }
  if(tid < B_) s_n[tid] = 0;
  if(tid == 0) tieCnt = 0;
  if(tid < 8) ((int*)cnt4)[tid] = 0;
  __syncthreads();

  unsigned p = 0;
  for(int it=0; it<16; ++it){
    const int bit = 30 - 2*it;
    int* A = cnt4[it&3];
    const unsigned q1 = p | (1u<<bit);
    const unsigned q2 = p | (2u<<bit);
    const unsigned q3 = p | (3u<<bit);
    int c1=0,c2=0,c3=0;
    for(int i=tid;i<total;i+=1024){
      unsigned x = ku[i];
      c1 += (x>=q1); c2 += (x>=q2); c3 += (x>=q3);
    }
    c1=waveRed(c1); c2=waveRed(c2); c3=waveRed(c3);
    if((tid&63)==0){ atomicAdd(&A[1],c1); atomicAdd(&A[2],c2); atomicAdd(&A[3],c3); }
    if(tid<4) cnt4[(it+2)&3][tid] = 0;
    __syncthreads();
    const int n1=A[1], n2=A[2], n3=A[3];
    if(n3>=k) p=q3; else if(n2>=k) p=q2; else if(n1>=k) p=q1;
  }
  __syncthreads();
  if(tid==0) scnt=0;
  __syncthreads();
  {
    int c=0;
    for(int i=tid;i<total;i+=1024) c += (ku[i] > p) ? 1 : 0;
    c = waveRed(c);
    if((tid&63)==0) atomicAdd(&scnt, c);
  }
  for(int i=tid;i<total;i+=1024){
    if(ku[i]==p){ int pos=atomicAdd(&tieCnt,1); if(pos<TIEMAX) tieIdx[pos]=i; }
  }
  __syncthreads();
  const int needed = k - scnt;

  for(int j=0;j<8;++j){
    int i = tid*8+j;
    ef[i] = (ku[i] > p) ? (short)1 : (short)0;
  }
  __syncthreads();

  if(tieCnt <= TIEMAX){
    if(tid==0){
      int cnt = tieCnt;
      for(int sel=0; sel<needed; ++sel){
        int best=INT_MAX, bi=-1;
        for(int q=0;q<cnt;++q){ int vv=tieIdx[q]; if(vv>=0 && vv<best){best=vv;bi=q;} }
        if(bi>=0){ tieIdx[bi]=-1; ef[best]=1; }
      }
    }
  } else {
    for(int j=0;j<8;++j){
      int i = tid*8+j;
      if(ku[i]==p){
        int r=0;
        for(int q=0;q<i;++q) r += (ku[q]==p) ? 1 : 0;
        if(r < needed) ef[i]=1;
      }
    }
  }
  __syncthreads();

  int own = 0;
  #pragma unroll
  for(int j=0;j<8;++j) own += ef[tid*8+j];
  csum[tid] = own;
  __syncthreads();
  for(int ofs=1; ofs<1024; ofs<<=1){
    int add = (tid>=ofs) ? csum[tid-ofs] : 0;
    __syncthreads();
    csum[tid] += add;
    __syncthreads();
  }
  if(tid < B_) batchPfx[tid] = (tid==0) ? 0 : csum[tid*256-1];
  if(tid == 0) batchPfx[B_] = csum[1023];
  __syncthreads();

  {
    const int ex = csum[tid] - own;
    int run = 0;
    for(int j=0;j<8;++j){
      int i = tid*8+j;
      if(ef[i]){
        int b = i >> 11;
        int t = i & (T_-1);
        int m = ex + run - batchPfx[b];
        if(t != T_-1){
          int c = T_-1-t; if(c>H) c=H;
          evTeSh[b*KSLOT+m] = (short)t;
          evEnSh[b*KSLOT+m] = (short)(t+c);
        }
        ++run;
      }
    }
  }
  __syncthreads();
  if(tid < B_){
    int nf = batchPfx[tid+1] - batchPfx[tid];
    nf -= (ef[tid*T_ + T_-1] ? 1 : 0);
    s_n[tid] = nf;
  }
  __syncthreads();
  if(tid==0){
    int off=0;
    for(int b=0;b<B_;++b){ meta[b]=s_n[b]; meta[4+b]=off; s_off[b]=off; off += s_n[b]; }
    meta[8] = off;  // nev
  }
  __syncthreads();

  for(int idx=tid; idx<B_*MAXMB; idx+=1024){
    const int b = idx>>10, m = idx & (MAXMB-1);
    const int n = s_n[b];
    if(m >= 2*n) continue;
    const short* S = evTeSh + b*KSLOT;
    const short* E = evEnSh + b*KSLOT;
    int rank, row, val;
    if(m < n){
      row = (int)S[m];
      rank = m + lowb_s(E, n, row);
      const int e = s_off[b] + m;
      val = e;
      const int en = (int)E[m];
      evB[e]=b; evCS[e]=row>>5; evCE[e]=en>>5;   // 32-row GROUP indices
      evInv[e] = 1.0f/(float)(en - row);
    } else {
      const int j = m - n;
      row = (int)E[j];
      rank = uppb_s(S, n, row) + j;
      val = (s_off[b] + j) | 0x8000;
    }
    markRowG[b*MAXMB+rank] = (unsigned short)row;
    markValG[b*MAXMB+rank] = (unsigned short)val;
  }

  for(int idx=tid; idx<B_*NCQ; idx+=1024){
    const int b = idx/NCQ, ch = idx%NCQ;
    const int n = s_n[b];
    const short* S = evTeSh + b*KSLOT;
    const short* E = evEnSh + b*KSLOT;
    const int lo = ch*TCQ, hi = lo+TCQ;
    const int a = lowb_s(S,n,lo) + lowb_s(E,n,lo);
    const int c = lowb_s(S,n,hi) + lowb_s(E,n,hi);
    mkStart[idx] = a; mkCnt[idx] = c - a;
  }

  for(int s=tid;s<T_;s+=1024){
    float acc = 0.f;
    int lo = s - H; if(lo < 0) lo = 0;
    for(int t2=lo; t2<s; ++t2){
      int c2 = T_-1-t2; if(c2 > H) c2 = H;
      acc += 1.0f / (float)c2;
    }
    w[s] = acc;
  }
}

// ---------------------------------------------------------------------------
// Kernel SQ v5: REGISTER pipeline, no LDS data staging (tests the gl_lds
// ceiling hypothesis). Each thread owns column d=tid*4 for its group's 32
// rows. Loads are opaque inline-asm global_load_dwordx4 (compiler cannot
// sink/split), 8 in flight, counted s_waitcnt vmcnt(7) + sched_barrier(0)
// fences. Iteration order: wait -> consume+mark-stores -> issue next load,
// so stores are always newer than any waited-on load (counting stays safe).
// LDS holds only marks + weights (~1KB).
// ---------------------------------------------------------------------------
__global__ __launch_bounds__(256) void kSQ(
    const float* __restrict__ states, const float* __restrict__ w,
    const int* __restrict__ mkStart, const int* __restrict__ mkCnt,
    const unsigned short* __restrict__ markRowG,
    const unsigned short* __restrict__ markValG,
    float4* __restrict__ Gbuf, float4* __restrict__ wA,
    float4* __restrict__ feS, float4* __restrict__ feE)
{
  __shared__ unsigned short sMr[MKCAP];
  __shared__ unsigned short sMv[MKCAP];
  __shared__ float sW[32];

  int bx = blockIdx.x;
  const int grp = bx & (NGRP-1); bx >>= 6;
  const int b = bx & 3; const int l = bx >> 2;
  const int tid = threadIdx.x;
  const int t0 = grp * 32;

  const int gBase = (b<<8) + grp*GRPC;
  const int mi0 = mkStart[gBase];
  int cnt = (mkStart[gBase+GRPC-1] + mkCnt[gBase+GRPC-1]) - mi0;
  if(cnt > MKCAP) cnt = MKCAP;
  for(int i=tid; i<cnt; i+=256){
    sMr[i] = markRowG[b*MAXMB + mi0 + i];
    sMv[i] = markValG[b*MAXMB + mi0 + i];
  }
  if(tid < 32) sW[tid] = w[t0 + tid];
  __syncthreads();   // LDS visible + vmcnt/lgkmcnt drained: clean counters

  int mi = 0;
  int nextRow = (cnt > 0) ? (int)sMr[0] : INT_MAX;
  f32x4 R = {0.f,0.f,0.f,0.f}, A = {0.f,0.f,0.f,0.f};

  unsigned long long a64 = (unsigned long long)(states
      + ((size_t)(l*B_+b)*T_ + t0)*D_) + (unsigned long long)tid*16ull;

  f32x4 x0,x1,x2,x3,x4,x5,x6,x7;

#define LOADX(xr_) { \
  asm volatile("global_load_dwordx4 %0, %1, off" : "=v"(xr_) : "v"(a64) : "memory"); \
  a64 += 4096ull; }

#define WAITV(n_) asm volatile("s_waitcnt vmcnt(" #n_ ")" ::: "memory")

#define CONSUME(r_, xr_) { \
    const int t = t0 + (r_); \
    float sx=xr_[0]*xr_[0], sy=xr_[1]*xr_[1], sz=xr_[2]*xr_[2], sw=xr_[3]*xr_[3]; \
    R[0]+=sx; R[1]+=sy; R[2]+=sz; R[3]+=sw; \
    const float wj = sW[r_]; \
    A[0]=fmaf(wj,sx,A[0]); A[1]=fmaf(wj,sy,A[1]); \
    A[2]=fmaf(wj,sz,A[2]); A[3]=fmaf(wj,sw,A[3]); \
    while(nextRow == t){ \
      const int me = (int)sMv[mi]; \
      float* dstp = (float*)(((me & 0x8000) ? feE : feS) \
                    + ((size_t)l*EVCAP + (me & 0x7fff))*256 + tid); \
      *(f32x4*)dstp = R; \
      ++mi; nextRow = (mi < cnt) ? (int)sMr[mi] : INT_MAX; } }

#define ITERL(r_, xr_) { WAITV(7); __builtin_amdgcn_sched_barrier(0); \
    CONSUME(r_, xr_); LOADX(xr_); }
#define ITERN(r_, xr_, n_) { WAITV(n_); __builtin_amdgcn_sched_barrier(0); \
    CONSUME(r_, xr_); }

  // prologue: 8 loads in flight
  LOADX(x0) LOADX(x1) LOADX(x2) LOADX(x3)
  LOADX(x4) LOADX(x5) LOADX(x6) LOADX(x7)

  ITERL(0,x0)  ITERL(1,x1)  ITERL(2,x2)  ITERL(3,x3)
  ITERL(4,x4)  ITERL(5,x5)  ITERL(6,x6)  ITERL(7,x7)
  ITERL(8,x0)  ITERL(9,x1)  ITERL(10,x2) ITERL(11,x3)
  ITERL(12,x4) ITERL(13,x5) ITERL(14,x6) ITERL(15,x7)
  ITERL(16,x0) ITERL(17,x1) ITERL(18,x2) ITERL(19,x3)
  ITERL(20,x4) ITERL(21,x5) ITERL(22,x6) ITERL(23,x7)
  ITERN(24,x0,7) ITERN(25,x1,6) ITERN(26,x2,5) ITERN(27,x3,4)
  ITERN(28,x4,3) ITERN(29,x5,2) ITERN(30,x6,1) ITERN(31,x7,0)

#undef LOADX
#undef WAITV
#undef CONSUME
#undef ITERL
#undef ITERN

  const size_t gi = ((size_t)(l*B_+b)*NGRP + grp)*256 + tid;
  *(f32x4*)((float*)(Gbuf + gi)) = R;    // 32-row group total
  *(f32x4*)((float*)(wA   + gi)) = A;
}

// ---------------------------------------------------------------------------
// Kernel Fin (byte-identical to R15).
// ---------------------------------------------------------------------------
__global__ __launch_bounds__(256) void kFin(
    const float* __restrict__ wAf, float* __restrict__ S_allP,
    const float4* __restrict__ Gbuf,
    const float4* __restrict__ feS, float4* __restrict__ feE,
    const int* __restrict__ evB, const int* __restrict__ evCS,
    const int* __restrict__ evCE, const float* __restrict__ evInv,
    const int* __restrict__ meta, float4* __restrict__ S_evP)
{
  const int tid = threadIdx.x;
  if(blockIdx.x < 128){
    const int dq = blockIdx.x & 3; const int lb = blockIdx.x >> 2;
    const int d = dq*256 + tid;
    const size_t base = (size_t)lb*NGRP*D_ + d;
    float aw = 0.f;
    for(int g0=0; g0<NGRP; g0+=8){
      float t[8];
      #pragma unroll
      for(int j=0;j<8;++j) t[j] = wAf[base + (size_t)(g0+j)*D_];
      #pragma unroll
      for(int j=0;j<8;++j) aw += t[j];
    }
    S_allP[(size_t)lb*D_ + d] = aw;
  } else {
    const int bid = blockIdx.x - 128;
    const int es = bid & 31; const int l = bid >> 5;
    const int nev = meta[8];
    const int per = (nev + 31) >> 5;
    const int e0 = es*per;
    int e1 = e0 + per; if(e1 > nev) e1 = nev;
    float4 E = {0,0,0,0};
    for(int e=e0; e<e1; ++e){
      const int b = evB[e], gs = evCS[e], ge = evCE[e];
      const float inv = evInv[e];
      const size_t sl = ((size_t)l*EVCAP + e)*256 + tid;
      float4 Rs = feS[sl], Re = feE[sl];
      float4 fe;
      if(gs == ge){
        fe.x=(Re.x-Rs.x)*inv; fe.y=(Re.y-Rs.y)*inv;
        fe.z=(Re.z-Rs.z)*inv; fe.w=(Re.w-Rs.w)*inv;
      } else {
        const size_t gb = ((size_t)(l*B_+b)*NGRP)*256 + tid;
        float4 acc = Gbuf[gb + (size_t)gs*256];
        acc.x-=Rs.x; acc.y-=Rs.y; acc.z-=Rs.z; acc.w-=Rs.w;
        for(int g=gs+1; g<ge; ++g){   // <=1 iteration (window <=64 rows)
          float4 Gv = Gbuf[gb + (size_t)g*256];
          acc.x+=Gv.x; acc.y+=Gv.y; acc.z+=Gv.z; acc.w+=Gv.w;
        }
        fe.x=(acc.x+Re.x)*inv; fe.y=(acc.y+Re.y)*inv;
        fe.z=(acc.z+Re.z)*inv; fe.w=(acc.w+Re.w)*inv;
      }
      feE[sl] = fe;
      E.x+=fe.x; E.y+=fe.y; E.z+=fe.z; E.w+=fe.w;
    }
    S_evP[((size_t)l*32 + es)*256 + tid] = E;
  }
}

// ---------------------------------------------------------------------------
// Kernel DS2 (byte-identical to R15).
// ---------------------------------------------------------------------------
__global__ __launch_bounds__(256) void kDS2(
    const float4* __restrict__ feE, const int* __restrict__ meta,
    const float4* __restrict__ S_allP, const float4* __restrict__ S_evP,
    const float4* __restrict__ baseline4,
    const float4* __restrict__ bank_ev4, const int* __restrict__ bank_step,
    const int* __restrict__ csptr,
    float4* __restrict__ out4, float4* __restrict__ S_exP,
    float4* __restrict__ SscoreP, int nonk)
{
  const int tid = threadIdx.x;
  if(blockIdx.x < 256){
    const int l = blockIdx.x >> 5, ech = blockIdx.x & 31;
    float4 sa = {0,0,0,0};
    #pragma unroll
    for(int b=0;b<B_;++b){
      float4 t = S_allP[((size_t)(l*B_+b))*256 + tid];
      sa.x+=t.x; sa.y+=t.y; sa.z+=t.z; sa.w+=t.w;
    }
    float4 se = {0,0,0,0};
    for(int j0=0;j0<32;j0+=8){
      float4 t[8];
      #pragma unroll
      for(int j=0;j<8;++j) t[j] = S_evP[((size_t)l*32 + j0+j)*256 + tid];
      #pragma unroll
      for(int j=0;j<8;++j){ se.x+=t[j].x; se.y+=t[j].y; se.z+=t[j].z; se.w+=t[j].w; }
    }
    const float inv_nonk = 1.0f/(float)nonk;
    const float4 bl = baseline4[(size_t)l*256 + tid];
    float4 nb;
    nb.x = 0.99f*bl.x + 0.01f*((sa.x-se.x)*inv_nonk);
    nb.y = 0.99f*bl.y + 0.01f*((sa.y-se.y)*inv_nonk);
    nb.z = 0.99f*bl.z + 0.01f*((sa.z-se.z)*inv_nonk);
    nb.w = 0.99f*bl.w + 0.01f*((sa.w-se.w)*inv_nonk);
    if(ech == 0) out4[2048 + (size_t)l*256 + tid] = nb;
    const int nev = meta[8];
    const int per = (nev + 31) >> 5;
    const int e0 = ech*per;
    int e1 = e0 + per; if(e1 > nev) e1 = nev;
    float4 acc = {0,0,0,0};
    #pragma unroll 4
    for(int e=e0;e<e1;++e){
      float4 fe = feE[((size_t)l*EVCAP + e)*256 + tid];
      acc.x += fmaxf(fe.x - nb.x, 0.f);
      acc.y += fmaxf(fe.y - nb.y, 0.f);
      acc.z += fmaxf(fe.z - nb.z, 0.f);
      acc.w += fmaxf(fe.w - nb.w, 0.f);
    }
    S_exP[((size_t)l*32 + ech)*256 + tid] = acc;
  } else {
    const int bx = blockIdx.x - 256;
    const int l = bx >> 5, sch = bx & 31;
    const int scount = TTL_/32;   // 32
    const int s0 = sch*scount;
    __shared__ float wl[TTL_/32];
    const int cs = csptr[0];
    if(tid < scount){
      int bs = bank_step[l*TTL_ + s0 + tid];
      float wgt = 0.f;
      if(bs >= 0){
        int a = cs - bs; if(a < 0) a = 0;
        wgt = exp2f(-(float)a * (1.0f/256.0f));
      }
      wl[tid] = wgt;
    }
    __syncthreads();
    float4 acc = {0,0,0,0};
    const float4* bp = bank_ev4 + ((size_t)l*TTL_ + s0)*256 + tid;
    #pragma unroll 8
    for(int j=0;j<scount;++j){
      float4 v = bp[(size_t)j*256];
      const float wv = wl[j];
      acc.x = fmaf(wv, v.x, acc.x); acc.y = fmaf(wv, v.y, acc.y);
      acc.z = fmaf(wv, v.z, acc.z); acc.w = fmaf(wv, v.w, acc.w);
    }
    SscoreP[((size_t)l*32 + sch)*256 + tid] = acc;
  }
}

// ---------------------------------------------------------------------------
// Kernel E (byte-identical to R15).
// ---------------------------------------------------------------------------
__global__ __launch_bounds__(256) void kE(
    const float4* __restrict__ S_exP, const float4* __restrict__ SscoreP,
    const int* __restrict__ bank_step, const int* __restrict__ csptr,
    float4* __restrict__ out4, float kf)
{
  const int l = blockIdx.x;
  const int tid = threadIdx.x;
  __shared__ float red[256];
  const int cs = csptr[0];
  float wacc = 0.f;
  for(int s=tid; s<TTL_; s+=256){
    int bs = bank_step[l*TTL_+s];
    if(bs >= 0){
      int a = cs - bs; if(a<0) a=0;
      wacc += exp2f(-(float)a * (1.0f/256.0f));
    }
  }
  red[tid] = wacc;
  __syncthreads();
  for(int st=128; st>0; st>>=1){ if(tid<st) red[tid] += red[tid+st]; __syncthreads(); }
  const float wsum = red[0];

  float4 ex = {0,0,0,0}, ss = {0,0,0,0};
  for(int j0=0;j0<32;j0+=8){
    float4 a[8], bb[8];
    #pragma unroll
    for(int j=0;j<8;++j){
      a[j]  = S_exP[((size_t)l*32 + j0+j)*256 + tid];
      bb[j] = SscoreP[((size_t)l*32 + j0+j)*256 + tid];
    }
    #pragma unroll
    for(int j=0;j<8;++j){
      ex.x+=a[j].x; ex.y+=a[j].y; ex.z+=a[j].z; ex.w+=a[j].w;
      ss.x+=bb[j].x; ss.y+=bb[j].y; ss.z+=bb[j].z; ss.w+=bb[j].w;
    }
  }
  const float invk = 1.0f/kf;
  float4 o0 = {ex.x*invk, ex.y*invk, ex.z*invk, ex.w*invk};
  out4[(size_t)l*256 + tid] = o0;
  float4 o2 = {0,0,0,0};
  if(wsum > 0.f){
    const float wm = fmaxf(wsum, 1e-12f);
    o2.x = ss.x/wm; o2.y = ss.y/wm; o2.z = ss.z/wm; o2.w = ss.w/wm;
  }
  out4[2*2048 + (size_t)l*256 + tid] = o2;
}

// ---------------------------------------------------------------------------
extern "C" void kernel_launch(void* const* d_in, const int* in_sizes, int n_in,
                              void* d_out, int out_size, void* d_ws, size_t ws_size,
                              hipStream_t stream)
{
  const float* pressure  = (const float*)d_in[0];
  const float* states    = (const float*)d_in[1];
  const float* bank_ev   = (const float*)d_in[2];
  const float* baseline  = (const float*)d_in[3];
  const int*   bank_step = (const int*)d_in[4];
  const int*   csptr     = (const int*)d_in[5];
  const int*   hptr      = (const int*)d_in[6];
  float* out = (float*)d_out;

  const int total = B_*T_;
  const int k = (int)llround(0.05 * (double)total);   // 410

  // workspace layout (bytes) — identical to R15, overlap-audited:
  char* ws = (char*)d_ws;
  float* w        = (float*)(ws + 0);
  int*   meta     = (int*)(ws + 8192);
  int*   evB      = (int*)(ws + 16384);
  int*   evCS     = (int*)(ws + 18432);
  int*   evCE     = (int*)(ws + 20480);
  float* evInv    = (float*)(ws + 22528);
  unsigned short* markRowG = (unsigned short*)(ws + 24576);
  unsigned short* markValG = (unsigned short*)(ws + 32768);
  int*   mkStart  = (int*)(ws + 40960);
  int*   mkCnt    = (int*)(ws + 45056);
  float* S_allP   = (float*)(ws + 65536);
  float* S_evP    = (float*)(ws + 262144);
  float* S_exP    = (float*)(ws + 1310720);
  float* SscoreP  = (float*)(ws + 2359296);
  float* Gbuf     = (float*)(ws + 4194304);    // 8 MB  -> 12582912
  float* wAbuf    = (float*)(ws + 12582912);   // 8 MB  -> 20971520
  float* feS      = (float*)(ws + 20971520);   // 16 MB -> 37748736
  float* feE      = (float*)(ws + 37748736);   // 16 MB -> 54525952

  const size_t need = 54525952ull;  // 52 MB
  if(ws_size < need) return;

  kA<<<1, 1024, 0, stream>>>(pressure, hptr, k, meta, w,
                             evB, evCS, evCE, evInv,
                             markRowG, markValG, mkStart, mkCnt);
  kSQ<<<L_*B_*NGRP, 256, 0, stream>>>(states, w, mkStart, mkCnt,
                                      markRowG, markValG,
                                      (float4*)Gbuf, (float4*)wAbuf,
                                      (float4*)feS, (float4*)feE);
  kFin<<<128 + 256, 256, 0, stream>>>(wAbuf, S_allP,
                                      (const float4*)Gbuf,
                                      (const float4*)feS, (float4*)feE,
                                      evB, evCS, evCE, evInv, meta,
                                      (float4*)S_evP);
  kDS2<<<512, 256, 0, stream>>>((const float4*)feE, meta,
                                (const float4*)S_allP, (const float4*)S_evP,
                                (const float4*)baseline,
                                (const float4*)bank_ev, bank_step, csptr,
                                (float4*)out, (float4*)S_exP,
                                (float4*)SscoreP, total - k);
  kE<<<L_, 256, 0, stream>>>((const float4*)S_exP, (const float4*)SscoreP,
                             bank_step, csptr, (float4*)out, (float)k);
}